// Round 7
// baseline (207.544 us; speedup 1.0000x reference)
//
#include <hip/hip_runtime.h>
#include <math.h>

constexpr int B_ = 4;
constexpr int N_ = 16384;
constexpr int DIN = 256;
constexpr int DOUT = 512;
constexpr int R_ = B_ * N_;   // 65536

typedef __attribute__((ext_vector_type(4))) float f32x4;
typedef __attribute__((ext_vector_type(8))) short short8;

// ---------------- workspace layout (float offsets) ----------------
constexpr size_t o_Gq    = 0;         // 256x256 query gram, part 0
constexpr size_t o_Gq2   = 65536;     // 256x256 query gram, part 1
constexpr size_t o_Gs    = 131072;    // 4 x 256x256 per-batch source grams
constexpr size_t o_uq    = 393216;    // 256 colsum(query)
constexpr size_t o_us    = 393472;    // 4x256 colsum(source_b)
constexpr size_t o_nrm   = 394496;    // [0]=nq2 [1]=nk2
constexpr size_t ZERO_FLOATS = 394498; // atomic region end
constexpr size_t o_Pv    = 394560;    // 4 x (256x512): G_b @ Wv^T
constexpr size_t o_Pk    = 918848;    // 4 x (256x512): G_b @ Wk^T
constexpr size_t o_Pq    = 1443136;   // 256x512: Gq @ Wq^T
constexpr size_t o_wku   = 1574208;   // 4x512
constexpr size_t o_wvu   = 1576256;   // 4x512
constexpr size_t o_kssum = 1578304;   // 4x512
constexpr size_t o_vssum = 1580352;   // 4x512
constexpr size_t o_kv    = 1582400;   // 4x8x64x64 raw K^T V
constexpr size_t o_W1bt  = 1713472;   // bf16: 4 x [512 c][256 k]  (s folded in)
constexpr size_t o_w2bt  = 1975616;   // bf16: 4 x [16 c][256 k]   (rows 8..15 zero)
constexpr size_t o_C1    = 1983808;   // 4x512 fp32
constexpr size_t o_C2    = 1985856;   // 4x8 fp32
constexpr size_t WS_FLOATS = 1985888; // ~7.9 MB (minimum)
// gram partials: bf16-packed (2 rows/u32), one 32768-u32 tile per block.
constexpr size_t o_part  = WS_FLOATS;                     // u32 units from here
constexpr size_t PART1_U32 = (size_t)8 * 64 * 32768;      // nb=64: 64 MB
constexpr size_t PART2_U32 = (size_t)8 * 32 * 32768;      // nb=32: 32 MB
constexpr size_t TIER1_FLOATS = WS_FLOATS + PART1_U32;    // ~75 MB total
constexpr size_t TIER2_FLOATS = WS_FLOATS + PART2_U32;    // ~41 MB total

static __device__ __forceinline__ float dot4(float4 a, float4 b) {
  return a.x * b.x + a.y * b.y + a.z * b.z + a.w * b.w;
}

// fp32 -> bf16 bits, round-to-nearest-even
static __device__ __forceinline__ unsigned short f2b(float f) {
  unsigned int u = __float_as_uint(f);
  u = (u + 0x7FFFu + ((u >> 16) & 1u)) >> 16;
  return (unsigned short)u;
}
static __device__ __forceinline__ float b2f_lo(unsigned int u) {
  return __uint_as_float(u << 16);
}
static __device__ __forceinline__ float b2f_hi(unsigned int u) {
  return __uint_as_float(u & 0xFFFF0000u);
}

// LDS swizzle for the gram transposed tile. Reads (16 consecutive cols per
// lane-group) see 8 slots / 2 lanes each = 2-way (free); writes (col stride 4)
// see 4 slots = 4-way (~1.6x on 4 instrs, negligible).
#define SWZ2(c) ((((c) >> 1) & 7) << 4)

// ---------------- 1) Grams: G = A^T A (256x256) + colsum, bf16 MFMA ----------------
// grid (nb, 8): z<4 -> source batch z ; z>=4 -> query quarter.
// Staging: 8x dwordx4 row loads per thread (1KB/wave-instr, 16B/lane) +
// in-register 8x4 transpose at bf16 pack time -> 4x ds_write_b128.
// (Replaces 32 scalar dword column loads: measured dword streaming caps the
//  whole kernel at 2.05 TB/s = 65us; dwordx4 is the m12->m17 fix.)
__global__ __launch_bounds__(512) void gram_k(const float* __restrict__ Xq,
                                              const float* __restrict__ Xsrc,
                                              float* __restrict__ ws,
                                              unsigned int* __restrict__ part) {
  const int z = blockIdx.y;
  const float* A;
  float* G;
  float* u;
  if (z < 4) {
    A = Xsrc + (size_t)z * N_ * DIN;
    G = ws + o_Gs + (size_t)z * 65536;
    u = ws + o_us + z * 256;
  } else {
    A = Xq + (size_t)(z - 4) * N_ * DIN;
    G = ws + ((z & 2) ? o_Gq2 : o_Gq);
    u = ws + o_uq;
  }
  const int nb = gridDim.x;
  const int rows_per_block = N_ / nb;       // 256 at nb=64
  const int nch = rows_per_block / 64;      // 4 at nb=64
  const int row0 = blockIdx.x * rows_per_block;
  const int tid = threadIdx.x;
  const int lane = tid & 63, wv = tid >> 6;
  const int i0w = (wv >> 1) * 64;           // wave tile: 64 (i) x 128 (j)
  const int j0w = (wv & 1) * 128;
  const int lc = lane & 15;
  const int klb = (lane >> 4) * 16;         // byte offset of this lane's k-octet

  // double-buffered transposed tile: [buf][256 cols][64 rows] bf16, swizzled
  __shared__ __align__(16) unsigned short As[2 * 256 * 64];   // 64 KB
  char* Ab = (char*)As;

  // staging mapping: thread owns cols cg*4..cg*4+3, row-octet wq within chunk
  const int cg = tid & 63;
  const int wq = tid >> 6;
  float cs[4] = {0.f, 0.f, 0.f, 0.f};      // per-thread colsum partials

  f32x4 acc[4][8] = {};

  for (int q = 0; q <= nch; ++q) {
    if (q < nch) {
      // stage chunk q into buffer (q&1): 8 row loads, transpose-pack, 4 writes
      const int bo = (q & 1) * 32768;
      const float* src = A + (size_t)(row0 + q * 64 + wq * 8) * DIN + cg * 4;
      f32x4 v[8];
#pragma unroll
      for (int g = 0; g < 8; ++g) v[g] = *(const f32x4*)(src + (size_t)g * DIN);
#pragma unroll
      for (int g = 0; g < 8; ++g) {
#pragma unroll
        for (int j = 0; j < 4; ++j) cs[j] += v[g][j];
      }
#pragma unroll
      for (int j = 0; j < 4; ++j) {
        short8 p;
#pragma unroll
        for (int e = 0; e < 8; ++e) p[e] = (short)f2b(v[e][j]);
        const int c = cg * 4 + j;
        *(short8*)(Ab + bo + ((c * 128 + wq * 16) ^ SWZ2(c))) = p;
      }
    }
    if (q > 0) {
      // compute chunk q-1 from the other buffer
      const char* srcb = Ab + (((q - 1) & 1) * 32768);
#pragma unroll
      for (int ks = 0; ks < 2; ++ks) {
        const int kbyte = ks * 64;
        short8 a[4], b[8];
#pragma unroll
        for (int fi = 0; fi < 4; ++fi) {
          const int cc = i0w + fi * 16 + lc;
          a[fi] = *(const short8*)(srcb + ((cc * 128 + kbyte + klb) ^ SWZ2(cc)));
        }
#pragma unroll
        for (int fj = 0; fj < 8; ++fj) {
          const int cc = j0w + fj * 16 + lc;
          b[fj] = *(const short8*)(srcb + ((cc * 128 + kbyte + klb) ^ SWZ2(cc)));
        }
#pragma unroll
        for (int fi = 0; fi < 4; ++fi)
#pragma unroll
          for (int fj = 0; fj < 8; ++fj)
            acc[fi][fj] = __builtin_amdgcn_mfma_f32_16x16x32_bf16(a[fi], b[fj], acc[fi][fj], 0, 0, 0);
      }
    }
    __syncthreads();
  }

  if (part) {
    // bf16-packed partial tile: u32 [128 row-pairs][256 cols]
    unsigned int* P = part + (size_t)(z * nb + blockIdx.x) * 32768;
#pragma unroll
    for (int fi = 0; fi < 4; ++fi) {
      const int ib = i0w + fi * 16 + (lane >> 4) * 4;   // multiple of 4
#pragma unroll
      for (int fj = 0; fj < 8; ++fj) {
        const int jb = j0w + fj * 16 + lc;
        const unsigned int p0 = (unsigned int)f2b(acc[fi][fj][0]) |
                                ((unsigned int)f2b(acc[fi][fj][1]) << 16);
        const unsigned int p1 = (unsigned int)f2b(acc[fi][fj][2]) |
                                ((unsigned int)f2b(acc[fi][fj][3]) << 16);
        P[(size_t)(ib >> 1) * 256 + jb] = p0;
        P[(size_t)((ib >> 1) + 1) * 256 + jb] = p1;
      }
    }
  } else {
    // fallback: device atomics
#pragma unroll
    for (int fi = 0; fi < 4; ++fi) {
      const int ib = i0w + fi * 16 + (lane >> 4) * 4;
#pragma unroll
      for (int fj = 0; fj < 8; ++fj) {
        const int jb = j0w + fj * 16 + lc;
#pragma unroll
        for (int r = 0; r < 4; ++r)
          atomicAdd(&G[(size_t)(ib + r) * DIN + jb], acc[fi][fj][r]);
      }
    }
  }

  // colsum reduce: red[8 wq][256 c] in LDS (reuse As), then 256-thread sum
  __syncthreads();
  float* red = (float*)As;
  *(float4*)&red[wq * 256 + cg * 4] = make_float4(cs[0], cs[1], cs[2], cs[3]);
  __syncthreads();
  if (tid < 256) {
    float s = 0.f;
#pragma unroll
    for (int pp = 0; pp < 8; ++pp) s += red[pp * 256 + tid];
    atomicAdd(&u[tid], s);
  }
}

// ---------------- 1b) reduce bf16 gram partials -> fp32 G buffers ----------------
// grid (64, 6): j<4 -> Gs[j] (np=nb); j=4 -> Gq (np=2nb); j=5 -> Gq2 (np=2nb)
__global__ __launch_bounds__(256) void gred_k(const unsigned int* __restrict__ part,
                                              float* __restrict__ ws, int nb) {
  const int j = blockIdx.y;
  int tile0, np;
  float* dst;
  if (j < 4) {
    tile0 = j * nb; np = nb; dst = ws + o_Gs + (size_t)j * 65536;
  } else if (j == 4) {
    tile0 = 4 * nb; np = 2 * nb; dst = ws + o_Gq;
  } else {
    tile0 = 6 * nb; np = 2 * nb; dst = ws + o_Gq2;
  }
  const int pt = blockIdx.x * 256 + threadIdx.x;  // 0..16383 (u32 pairs)
  const int t0 = pt * 2;
  const int ip = t0 >> 8, jj = t0 & 255;
  const unsigned int* src = part + (size_t)tile0 * 32768 + (size_t)ip * 256 + jj;
  float s00 = 0.f, s01 = 0.f, s10 = 0.f, s11 = 0.f;
  for (int p = 0; p < np; ++p) {
    const uint2 v = *(const uint2*)&src[(size_t)p * 32768];
    s00 += b2f_lo(v.x); s10 += b2f_hi(v.x);
    s01 += b2f_lo(v.y); s11 += b2f_hi(v.y);
  }
  *(float2*)&dst[(size_t)(2 * ip) * 256 + jj] = make_float2(s00, s01);
  *(float2*)&dst[(size_t)(2 * ip + 1) * 256 + jj] = make_float2(s10, s11);
}

// ---------------- 2) P = G @ W^T  (256x512, K=256) ----------------
// grid (8 ctiles, 4 itiles, 9 jobs); job 8 sums Gq + Gq2 on the fly
__global__ __launch_bounds__(256) void p_k(const float* __restrict__ Wq,
                                           const float* __restrict__ Wk,
                                           const float* __restrict__ Wv,
                                           float* __restrict__ ws) {
  const int job = blockIdx.z;
  const float* G;
  const float* G2 = nullptr;
  const float* W;
  float* P;
  if (job < 4) {
    G = ws + o_Gs + (size_t)job * 65536; W = Wv; P = ws + o_Pv + (size_t)job * 131072;
  } else if (job < 8) {
    G = ws + o_Gs + (size_t)(job - 4) * 65536; W = Wk; P = ws + o_Pk + (size_t)(job - 4) * 131072;
  } else {
    G = ws + o_Gq; G2 = ws + o_Gq2; W = Wq; P = ws + o_Pq;
  }
  const int c0 = blockIdx.x * 64, i0 = blockIdx.y * 64;
  __shared__ float Gt[64][68];
  __shared__ float Wt[64][68];
  const int tid = threadIdx.x;
  const int ty = tid >> 4, tx = tid & 15;
  float acc[4][4] = {};
  for (int k0 = 0; k0 < 256; k0 += 64) {
    __syncthreads();
#pragma unroll
    for (int pg = 0; pg < 4; ++pg) {
      const int idx = tid + pg * 256;
      const int row = idx >> 4, jq = (idx & 15) * 4;
      float4 g = *(const float4*)&G[(size_t)(i0 + row) * DIN + k0 + jq];
      if (G2) {
        const float4 h = *(const float4*)&G2[(size_t)(i0 + row) * DIN + k0 + jq];
        g.x += h.x; g.y += h.y; g.z += h.z; g.w += h.w;
      }
      Gt[jq + 0][row] = g.x; Gt[jq + 1][row] = g.y; Gt[jq + 2][row] = g.z; Gt[jq + 3][row] = g.w;
      const float4 w = *(const float4*)&W[(size_t)(c0 + row) * DIN + k0 + jq];
      Wt[jq + 0][row] = w.x; Wt[jq + 1][row] = w.y; Wt[jq + 2][row] = w.z; Wt[jq + 3][row] = w.w;
    }
    __syncthreads();
#pragma unroll
    for (int k = 0; k < 64; ++k) {
      const float4 a = *(const float4*)&Gt[k][ty * 4];
      const float4 bb = *(const float4*)&Wt[k][tx * 4];
      const float av[4] = {a.x, a.y, a.z, a.w};
      const float bv_[4] = {bb.x, bb.y, bb.z, bb.w};
#pragma unroll
      for (int ii = 0; ii < 4; ++ii)
#pragma unroll
        for (int jj = 0; jj < 4; ++jj) acc[ii][jj] += av[ii] * bv_[jj];
    }
  }
#pragma unroll
  for (int ii = 0; ii < 4; ++ii)
    *(float4*)&P[(size_t)(i0 + ty * 4 + ii) * DOUT + c0 + tx * 4] =
        make_float4(acc[ii][0], acc[ii][1], acc[ii][2], acc[ii][3]);
}

// ---------------- 3) small bilinears: wku/wvu, ks_sum/vs_sum, nq2/nk2 ----------------
__global__ __launch_bounds__(256) void s1_k(const float* __restrict__ Wq,
                                            const float* __restrict__ Wk,
                                            const float* __restrict__ Wv,
                                            const float* __restrict__ bq,
                                            const float* __restrict__ bk,
                                            const float* __restrict__ bv,
                                            float* __restrict__ ws) {
  const int tid = threadIdx.x;
  const int c = blockIdx.x * 64 + (tid >> 2);
  const int part = tid & 3;
  const int i0 = part * 64;
  const int job = blockIdx.y;
  __shared__ float red[256];
  float np = 0.f;
  if (job < 4) {
    const int b = job;
    const float* ub = ws + o_us + b * 256;
    const float* wkr = Wk + (size_t)c * 256;
    const float* wvr = Wv + (size_t)c * 256;
    const float* pk = ws + o_Pk + (size_t)b * 131072 + c;
    float dku = 0.f, dvu = 0.f, dpk = 0.f;
#pragma unroll 4
    for (int t = 0; t < 16; ++t) {
      const float4 u4 = *(const float4*)&ub[i0 + t * 4];
      dku += dot4(*(const float4*)&wkr[i0 + t * 4], u4);
      dvu += dot4(*(const float4*)&wvr[i0 + t * 4], u4);
    }
    for (int i = i0; i < i0 + 64; ++i) dpk += wkr[i] * pk[(size_t)i * 512];
    dku += __shfl_down(dku, 2); dku += __shfl_down(dku, 1);
    dvu += __shfl_down(dvu, 2); dvu += __shfl_down(dvu, 1);
    dpk += __shfl_down(dpk, 2); dpk += __shfl_down(dpk, 1);
    if (part == 0) {
      ws[o_wku + b * 512 + c] = dku;
      ws[o_wvu + b * 512 + c] = dvu;
      ws[o_kssum + b * 512 + c] = dku + (float)N_ * bk[c];
      ws[o_vssum + b * 512 + c] = dvu + (float)N_ * bv[c];
      np = dpk + 2.f * bk[c] * dku + (float)N_ * bk[c] * bk[c];
    }
    red[tid] = np;
    __syncthreads();
    for (int s = 128; s > 0; s >>= 1) {
      if (tid < s) red[tid] += red[tid + s];
      __syncthreads();
    }
    if (tid == 0) atomicAdd(&ws[o_nrm + 1], red[0]);
  } else {
    const float* uq = ws + o_uq;
    const float* wqr = Wq + (size_t)c * 256;
    const float* pq = ws + o_Pq + c;
    float dqu = 0.f, dpq = 0.f;
#pragma unroll 4
    for (int t = 0; t < 16; ++t)
      dqu += dot4(*(const float4*)&wqr[i0 + t * 4], *(const float4*)&uq[i0 + t * 4]);
    for (int i = i0; i < i0 + 64; ++i) dpq += wqr[i] * pq[(size_t)i * 512];
    dqu += __shfl_down(dqu, 2); dqu += __shfl_down(dqu, 1);
    dpq += __shfl_down(dpq, 2); dpq += __shfl_down(dpq, 1);
    if (part == 0) np = dpq + 2.f * bq[c] * dqu + (float)R_ * bq[c] * bq[c];
    red[tid] = np;
    __syncthreads();
    for (int s = 128; s > 0; s >>= 1) {
      if (tid < s) red[tid] += red[tid + s];
      __syncthreads();
    }
    if (tid == 0) atomicAdd(&ws[o_nrm], red[0]);
  }
}

// ---------------- 4) kv[b,h] = Wk_h (G_b Wv_h^T) + rank-1 terms ----------------
__global__ __launch_bounds__(256) void kv_k(const float* __restrict__ Wk,
                                            const float* __restrict__ bk,
                                            const float* __restrict__ bv,
                                            float* __restrict__ ws) {
  const int bh = blockIdx.x, b = bh >> 3, h = bh & 7;
  const int o0 = blockIdx.y * 1024 + threadIdx.x * 4;
  const int m = o0 >> 6, d0 = o0 & 63;
  const float* pv = ws + o_Pv + (size_t)b * 131072 + h * 64 + d0;
  const float* wk = Wk + (size_t)(h * 64 + m) * 256;
  float acc[4] = {0.f, 0.f, 0.f, 0.f};
  for (int i = 0; i < 256; ++i) {
    const float w = wk[i];
    const float4 p = *(const float4*)&pv[(size_t)i * 512];
    acc[0] += w * p.x; acc[1] += w * p.y; acc[2] += w * p.z; acc[3] += w * p.w;
  }
  const float wkum = ws[o_wku + b * 512 + h * 64 + m];
  const float bkm = bk[h * 64 + m];
  const float* wvup = ws + o_wvu + b * 512 + h * 64 + d0;
  const float* bvp = bv + h * 64 + d0;
  float rr[4];
#pragma unroll
  for (int e = 0; e < 4; ++e)
    rr[e] = acc[e] + wkum * bvp[e] + bkm * wvup[e] + (float)N_ * bkm * bvp[e];
  *(float4*)&ws[o_kv + (size_t)bh * 4096 + (size_t)m * 64 + d0] =
      make_float4(rr[0], rr[1], rr[2], rr[3]);
}

// ---------------- 5) W1bt/w2bt (bf16, K-major) + C1/C2 (fp32), fold s ----------------
// grid (4 b, 256 i), 512 threads
__global__ __launch_bounds__(512) void w1_k(const float* __restrict__ Wq,
                                            const float* __restrict__ bq,
                                            float* __restrict__ ws) {
  const int b = blockIdx.x, i = blockIdx.y;
  const int c = threadIdx.x, h = c >> 6, d = c & 63;
  const float s = 1.f / (sqrtf(ws[o_nrm]) * sqrtf(ws[o_nrm + 1]));
  const float* kvp = ws + o_kv + (size_t)(b * 8 + h) * 4096 + d;
  unsigned short* W1bt = (unsigned short*)(ws + o_W1bt) + (size_t)b * 131072;
  unsigned short* w2bt = (unsigned short*)(ws + o_w2bt) + b * 4096;
  float a = 0.f;
#pragma unroll 4
  for (int m = 0; m < 64; ++m) a += Wq[(size_t)(h * 64 + m) * 256 + i] * kvp[(size_t)m * 64];
  W1bt[(size_t)c * 256 + i] = f2b(s * a);
  if (c < 16) {
    float w = 0.f;
    if (c < 8) {
      const float* ksp = ws + o_kssum + b * 512 + c * 64;
#pragma unroll 4
      for (int m = 0; m < 64; ++m) w += Wq[(size_t)(c * 64 + m) * 256 + i] * ksp[m];
    }
    w2bt[c * 256 + i] = f2b(s * w);
  }
  if (i == 0) {
    float c1 = 0.f;
    for (int m = 0; m < 64; ++m) c1 += bq[h * 64 + m] * kvp[(size_t)m * 64];
    ws[o_C1 + b * 512 + c] = s * c1 + ws[o_vssum + b * 512 + c];
    if (c < 8) {
      float c2 = 0.f;
      const float* ksp = ws + o_kssum + b * 512 + c * 64;
      for (int m = 0; m < 64; ++m) c2 += bq[c * 64 + m] * ksp[m];
      ws[o_C2 + b * 8 + c] = s * c2 + (float)N_;
    }
  }
}

// ---------------- 6) output: num/den via bf16 MFMA + fused epilogue ----------------
// grid (R/64), 256 threads (4 waves). Wave w owns output cols d = w*16.. for ALL 8 heads.
__global__ __launch_bounds__(256) void out_k(const float* __restrict__ X,
                                             const float* __restrict__ ws,
                                             float* __restrict__ out) {
  const int r0 = blockIdx.x * 64;
  const int b = blockIdx.x >> 8;
  const int tid = threadIdx.x;
  const int lane = tid & 63, wv = tid >> 6;
  const int lc = lane & 15;
  const int klb = (lane >> 4) * 16;

  __shared__ __align__(16) unsigned short Xs[64 * 256];
  __shared__ float invden[64][9];
  char* Xb = (char*)Xs;

  {
    const int row = tid >> 2, kq = (tid & 3) * 64;
    const float* src = X + (size_t)(r0 + row) * DIN + kq;
    const int swz = (row & 7) << 4;
#pragma unroll
    for (int g = 0; g < 8; ++g) {
      const float4 v0 = *(const float4*)(src + g * 8);
      const float4 v1 = *(const float4*)(src + g * 8 + 4);
      short8 p;
      p[0] = (short)f2b(v0.x); p[1] = (short)f2b(v0.y);
      p[2] = (short)f2b(v0.z); p[3] = (short)f2b(v0.w);
      p[4] = (short)f2b(v1.x); p[5] = (short)f2b(v1.y);
      p[6] = (short)f2b(v1.z); p[7] = (short)f2b(v1.w);
      *(short8*)(Xb + ((row * 512 + (kq + g * 8) * 2) ^ swz)) = p;
    }
  }
  __syncthreads();

  const char* W1b = (const char*)((const unsigned short*)(ws + o_W1bt) + (size_t)b * 131072);
  const char* w2b = (const char*)((const unsigned short*)(ws + o_w2bt) + b * 4096);

  f32x4 acc[4][8] = {};
  f32x4 acc2[4] = {};
#pragma unroll
  for (int k32 = 0; k32 < 8; ++k32) {
    const int kbyte = k32 * 64;
    short8 a[4];
#pragma unroll
    for (int fi = 0; fi < 4; ++fi) {
      const int row = fi * 16 + lc;
      a[fi] = *(const short8*)(Xb + ((row * 512 + kbyte + klb) ^ ((row & 7) << 4)));
    }
    short8 bb[8];
#pragma unroll
    for (int fj = 0; fj < 8; ++fj) {
      const int cc = fj * 64 + wv * 16 + lc;
      bb[fj] = *(const short8*)(W1b + cc * 512 + kbyte + klb);
    }
    if (wv == 0) {
      const short8 b2 = *(const short8*)(w2b + lc * 512 + kbyte + klb);
#pragma unroll
      for (int fi = 0; fi < 4; ++fi)
        acc2[fi] = __builtin_amdgcn_mfma_f32_16x16x32_bf16(a[fi], b2, acc2[fi], 0, 0, 0);
    }
#pragma unroll
    for (int fi = 0; fi < 4; ++fi)
#pragma unroll
      for (int fj = 0; fj < 8; ++fj)
        acc[fi][fj] = __builtin_amdgcn_mfma_f32_16x16x32_bf16(a[fi], bb[fj], acc[fi][fj], 0, 0, 0);
  }

  if (wv == 0 && lc < 8) {
    const float c2 = ws[o_C2 + b * 8 + lc];
#pragma unroll
    for (int fi = 0; fi < 4; ++fi) {
      const int rb = fi * 16 + (lane >> 4) * 4;
#pragma unroll
      for (int r = 0; r < 4; ++r) invden[rb + r][lc] = 1.f / (acc2[fi][r] + c2);
    }
  }
  __syncthreads();

  const float* C1p = ws + o_C1 + b * 512;
  float cf[8];
#pragma unroll
  for (int fj = 0; fj < 8; ++fj) cf[fj] = C1p[fj * 64 + wv * 16 + lc];

#pragma unroll
  for (int fi = 0; fi < 4; ++fi) {
    const int rb = fi * 16 + (lane >> 4) * 4;
    float o[4] = {0.f, 0.f, 0.f, 0.f};
#pragma unroll
    for (int fj = 0; fj < 8; ++fj)
#pragma unroll
      for (int r = 0; r < 4; ++r)
        o[r] += (acc[fi][fj][r] + cf[fj]) * invden[rb + r][fj];
#pragma unroll
    for (int r = 0; r < 4; ++r)
      out[(size_t)(r0 + rb + r) * 64 + wv * 16 + lc] = o[r] * 0.125f;
  }
}

extern "C" void kernel_launch(void* const* d_in, const int* in_sizes, int n_in,
                              void* d_out, int out_size, void* d_ws, size_t ws_size,
                              hipStream_t stream) {
  const float* Xq = (const float*)d_in[0];
  const float* Xsrc = (const float*)d_in[1];
  const float* Wq = (const float*)d_in[2];
  const float* bq = (const float*)d_in[3];
  const float* Wk = (const float*)d_in[4];
  const float* bk = (const float*)d_in[5];
  const float* Wv = (const float*)d_in[6];
  const float* bv = (const float*)d_in[7];
  float* out = (float*)d_out;
  float* ws = (float*)d_ws;
  if (ws_size < WS_FLOATS * sizeof(float)) return;  // need >= 7.9 MB scratch

  int nb = 0;                                        // blocks per z (0 = atomic fallback)
  if (ws_size >= TIER1_FLOATS * sizeof(float)) nb = 64;
  else if (ws_size >= TIER2_FLOATS * sizeof(float)) nb = 32;
  unsigned int* part = nb ? (unsigned int*)(ws + o_part) : nullptr;

  if (nb) {
    // only colsums + norms are atomically accumulated on the fast path
    hipMemsetAsync(ws + o_uq, 0, (ZERO_FLOATS - o_uq) * sizeof(float), stream);
    gram_k<<<dim3(nb, 8), 512, 0, stream>>>(Xq, Xsrc, ws, part);
    gred_k<<<dim3(64, 6), 256, 0, stream>>>(part, ws, nb);
  } else {
    hipMemsetAsync(ws, 0, ZERO_FLOATS * sizeof(float), stream);
    gram_k<<<dim3(32, 8), 512, 0, stream>>>(Xq, Xsrc, ws, nullptr);
  }
  p_k<<<dim3(8, 4, 9), 256, 0, stream>>>(Wq, Wk, Wv, ws);
  s1_k<<<dim3(8, 5), 256, 0, stream>>>(Wq, Wk, Wv, bq, bk, bv, ws);
  kv_k<<<dim3(32, 4), 256, 0, stream>>>(Wk, bk, bv, ws);
  w1_k<<<dim3(4, 256), 512, 0, stream>>>(Wq, bq, ws);
  out_k<<<dim3(1024), 256, 0, stream>>>(Xq, ws, out);
}

// Round 8
// 205.203 us; speedup vs baseline: 1.0114x; 1.0114x over previous
//
#include <hip/hip_runtime.h>
#include <math.h>

constexpr int B_ = 4;
constexpr int N_ = 16384;
constexpr int DIN = 256;
constexpr int DOUT = 512;
constexpr int R_ = B_ * N_;   // 65536

typedef __attribute__((ext_vector_type(4))) float f32x4;
typedef __attribute__((ext_vector_type(8))) short short8;

// ---------------- workspace layout (float offsets) ----------------
constexpr size_t o_Gq    = 0;         // 256x256 query gram, part 0
constexpr size_t o_Gq2   = 65536;     // 256x256 query gram, part 1
constexpr size_t o_Gs    = 131072;    // 4 x 256x256 per-batch source grams
constexpr size_t o_SK    = 393216;    // 256x256 Wk^T Wk   (atomic-accumulated)
constexpr size_t o_SQ    = 458752;    // 256x256 Wq^T Wq   (atomic-accumulated)
constexpr size_t o_uq    = 524288;    // 256 colsum(query)
constexpr size_t o_us    = 524544;    // 4x256 colsum(source_b)
constexpr size_t o_nrm   = 525568;    // [0]=nq2 [1]=nk2
constexpr size_t ZERO_END = 525570;   // atomic region: o_SK..here (fast), 0..here (fallback)
constexpr size_t o_Pv    = 525632;    // 4 x (256x512): G_b @ Wv^T
constexpr size_t o_wku   = 1049920;   // 4x512
constexpr size_t o_wvu   = 1051968;   // 4x512
constexpr size_t o_kssum = 1054016;   // 4x512
constexpr size_t o_vssum = 1056064;   // 4x512
constexpr size_t o_kv    = 1058112;   // 4x8x64x64 raw K^T V
constexpr size_t o_W1bt  = 1189184;   // bf16: 4 x [512 c][256 k]  (s folded in)
constexpr size_t o_w2bt  = 1451328;   // bf16: 4 x [16 c][256 k]   (rows 8..15 zero)
constexpr size_t o_C1    = 1459520;   // 4x512 fp32
constexpr size_t o_C2    = 1461568;   // 4x8 fp32
constexpr size_t WS_FLOATS = 1461600; // ~5.9 MB (minimum)
// gram partials: bf16-packed (2 rows/u32), one 32768-u32 tile per block.
constexpr size_t o_part  = WS_FLOATS;                     // u32 units from here
constexpr size_t PART1_U32 = (size_t)8 * 64 * 32768;      // nb=64: 64 MB
constexpr size_t PART2_U32 = (size_t)8 * 32 * 32768;      // nb=32: 32 MB
constexpr size_t TIER1_FLOATS = WS_FLOATS + PART1_U32;    // ~73 MB total
constexpr size_t TIER2_FLOATS = WS_FLOATS + PART2_U32;    // ~39 MB total

static __device__ __forceinline__ float dot4(float4 a, float4 b) {
  return a.x * b.x + a.y * b.y + a.z * b.z + a.w * b.w;
}
static __device__ __forceinline__ float dot4v(f32x4 a, f32x4 b) {
  return a[0] * b[0] + a[1] * b[1] + a[2] * b[2] + a[3] * b[3];
}

// fp32 -> bf16 bits, round-to-nearest-even
static __device__ __forceinline__ unsigned short f2b(float f) {
  unsigned int u = __float_as_uint(f);
  u = (u + 0x7FFFu + ((u >> 16) & 1u)) >> 16;
  return (unsigned short)u;
}
static __device__ __forceinline__ float b2f_lo(unsigned int u) {
  return __uint_as_float(u << 16);
}
static __device__ __forceinline__ float b2f_hi(unsigned int u) {
  return __uint_as_float(u & 0xFFFF0000u);
}

#define SWZ2(c) ((((c) >> 1) & 7) << 4)

// ---------------- 1) Grams: G = A^T A (256x256) + colsum, bf16 MFMA ----------------
// (R6 version, unchanged: occupancy-locked at ~62us, accepted this round)
__global__ __launch_bounds__(512) void gram_k(const float* __restrict__ Xq,
                                              const float* __restrict__ Xsrc,
                                              float* __restrict__ ws,
                                              unsigned int* __restrict__ part) {
  const int z = blockIdx.y;
  const float* A;
  float* G;
  float* u;
  if (z < 4) {
    A = Xsrc + (size_t)z * N_ * DIN;
    G = ws + o_Gs + (size_t)z * 65536;
    u = ws + o_us + z * 256;
  } else {
    A = Xq + (size_t)(z - 4) * N_ * DIN;
    G = ws + ((z & 2) ? o_Gq2 : o_Gq);
    u = ws + o_uq;
  }
  const int nb = gridDim.x;
  const int rows_per_block = N_ / nb;
  const int nch = rows_per_block / 64;
  const int row0 = blockIdx.x * rows_per_block;
  const int tid = threadIdx.x;
  const int lane = tid & 63, wv = tid >> 6;
  const int i0w = (wv >> 1) * 64;
  const int j0w = (wv & 1) * 128;
  const int lc = lane & 15;
  const int klb = (lane >> 4) * 16;

  __shared__ __align__(16) unsigned short As[2 * 256 * 64];   // 64 KB dbuf
  char* Ab = (char*)As;

  const int cg = tid & 63;
  const int wq = tid >> 6;
  float cs[4] = {0.f, 0.f, 0.f, 0.f};

  f32x4 acc[4][8] = {};

  for (int q = 0; q <= nch; ++q) {
    if (q < nch) {
      const int bo = (q & 1) * 32768;
      const float* src = A + (size_t)(row0 + q * 64 + wq * 8) * DIN + cg * 4;
      f32x4 v[8];
#pragma unroll
      for (int g = 0; g < 8; ++g) v[g] = *(const f32x4*)(src + (size_t)g * DIN);
#pragma unroll
      for (int g = 0; g < 8; ++g) {
#pragma unroll
        for (int j = 0; j < 4; ++j) cs[j] += v[g][j];
      }
#pragma unroll
      for (int j = 0; j < 4; ++j) {
        short8 p;
#pragma unroll
        for (int e = 0; e < 8; ++e) p[e] = (short)f2b(v[e][j]);
        const int c = cg * 4 + j;
        *(short8*)(Ab + bo + ((c * 128 + wq * 16) ^ SWZ2(c))) = p;
      }
    }
    if (q > 0) {
      const char* srcb = Ab + (((q - 1) & 1) * 32768);
#pragma unroll
      for (int ks = 0; ks < 2; ++ks) {
        const int kbyte = ks * 64;
        short8 a[4], b[8];
#pragma unroll
        for (int fi = 0; fi < 4; ++fi) {
          const int cc = i0w + fi * 16 + lc;
          a[fi] = *(const short8*)(srcb + ((cc * 128 + kbyte + klb) ^ SWZ2(cc)));
        }
#pragma unroll
        for (int fj = 0; fj < 8; ++fj) {
          const int cc = j0w + fj * 16 + lc;
          b[fj] = *(const short8*)(srcb + ((cc * 128 + kbyte + klb) ^ SWZ2(cc)));
        }
#pragma unroll
        for (int fi = 0; fi < 4; ++fi)
#pragma unroll
          for (int fj = 0; fj < 8; ++fj)
            acc[fi][fj] = __builtin_amdgcn_mfma_f32_16x16x32_bf16(a[fi], b[fj], acc[fi][fj], 0, 0, 0);
      }
    }
    __syncthreads();
  }

  if (part) {
    unsigned int* P = part + (size_t)(z * nb + blockIdx.x) * 32768;
#pragma unroll
    for (int fi = 0; fi < 4; ++fi) {
      const int ib = i0w + fi * 16 + (lane >> 4) * 4;
#pragma unroll
      for (int fj = 0; fj < 8; ++fj) {
        const int jb = j0w + fj * 16 + lc;
        const unsigned int p0 = (unsigned int)f2b(acc[fi][fj][0]) |
                                ((unsigned int)f2b(acc[fi][fj][1]) << 16);
        const unsigned int p1 = (unsigned int)f2b(acc[fi][fj][2]) |
                                ((unsigned int)f2b(acc[fi][fj][3]) << 16);
        P[(size_t)(ib >> 1) * 256 + jb] = p0;
        P[(size_t)((ib >> 1) + 1) * 256 + jb] = p1;
      }
    }
  } else {
#pragma unroll
    for (int fi = 0; fi < 4; ++fi) {
      const int ib = i0w + fi * 16 + (lane >> 4) * 4;
#pragma unroll
      for (int fj = 0; fj < 8; ++fj) {
        const int jb = j0w + fj * 16 + lc;
#pragma unroll
        for (int r = 0; r < 4; ++r)
          atomicAdd(&G[(size_t)(ib + r) * DIN + jb], acc[fi][fj][r]);
      }
    }
  }

  __syncthreads();
  float* red = (float*)As;
  *(float4*)&red[wq * 256 + cg * 4] = make_float4(cs[0], cs[1], cs[2], cs[3]);
  __syncthreads();
  if (tid < 256) {
    float s = 0.f;
#pragma unroll
    for (int pp = 0; pp < 8; ++pp) s += red[pp * 256 + tid];
    atomicAdd(&u[tid], s);
  }
}

// ---------------- 1w) weight grams: S_K = Wk^T Wk, S_Q = Wq^T Wq ----------------
// grid (8, 2): z=0 -> Wk, z=1 -> Wq. One 64-row chunk per block; fp32 atomics out.
__global__ __launch_bounds__(512) void wgram_k(const float* __restrict__ Wk,
                                               const float* __restrict__ Wq,
                                               float* __restrict__ ws) {
  const int z = blockIdx.y;
  const float* A = z ? Wq : Wk;
  float* S = ws + (z ? o_SQ : o_SK);
  const int row0 = blockIdx.x * 64;
  const int tid = threadIdx.x;
  const int lane = tid & 63, wv = tid >> 6;
  const int i0w = (wv >> 1) * 64;
  const int j0w = (wv & 1) * 128;
  const int lc = lane & 15;
  const int klb = (lane >> 4) * 16;

  __shared__ __align__(16) unsigned short As[256 * 64];   // 32 KB
  char* Ab = (char*)As;

  const int cg = tid & 63;
  const int wq = tid >> 6;
  {
    const float* src = A + (size_t)(row0 + wq * 8) * DIN + cg * 4;
    f32x4 v[8];
#pragma unroll
    for (int g = 0; g < 8; ++g) v[g] = *(const f32x4*)(src + (size_t)g * DIN);
#pragma unroll
    for (int j = 0; j < 4; ++j) {
      short8 p;
#pragma unroll
      for (int e = 0; e < 8; ++e) p[e] = (short)f2b(v[e][j]);
      const int c = cg * 4 + j;
      *(short8*)(Ab + ((c * 128 + wq * 16) ^ SWZ2(c))) = p;
    }
  }
  __syncthreads();
  f32x4 acc[4][8] = {};
#pragma unroll
  for (int ks = 0; ks < 2; ++ks) {
    const int kbyte = ks * 64;
    short8 a[4], b[8];
#pragma unroll
    for (int fi = 0; fi < 4; ++fi) {
      const int cc = i0w + fi * 16 + lc;
      a[fi] = *(const short8*)(Ab + ((cc * 128 + kbyte + klb) ^ SWZ2(cc)));
    }
#pragma unroll
    for (int fj = 0; fj < 8; ++fj) {
      const int cc = j0w + fj * 16 + lc;
      b[fj] = *(const short8*)(Ab + ((cc * 128 + kbyte + klb) ^ SWZ2(cc)));
    }
#pragma unroll
    for (int fi = 0; fi < 4; ++fi)
#pragma unroll
      for (int fj = 0; fj < 8; ++fj)
        acc[fi][fj] = __builtin_amdgcn_mfma_f32_16x16x32_bf16(a[fi], b[fj], acc[fi][fj], 0, 0, 0);
  }
#pragma unroll
  for (int fi = 0; fi < 4; ++fi) {
    const int ib = i0w + fi * 16 + (lane >> 4) * 4;
#pragma unroll
    for (int fj = 0; fj < 8; ++fj) {
      const int jb = j0w + fj * 16 + lc;
#pragma unroll
      for (int r = 0; r < 4; ++r)
        atomicAdd(&S[(size_t)(ib + r) * DIN + jb], acc[fi][fj][r]);
    }
  }
}

// ---------------- 1b) reduce bf16 gram partials -> fp32 G buffers ----------------
__global__ __launch_bounds__(256) void gred_k(const unsigned int* __restrict__ part,
                                              float* __restrict__ ws, int nb) {
  const int j = blockIdx.y;
  int tile0, np;
  float* dst;
  if (j < 4) {
    tile0 = j * nb; np = nb; dst = ws + o_Gs + (size_t)j * 65536;
  } else if (j == 4) {
    tile0 = 4 * nb; np = 2 * nb; dst = ws + o_Gq;
  } else {
    tile0 = 6 * nb; np = 2 * nb; dst = ws + o_Gq2;
  }
  const int pt = blockIdx.x * 256 + threadIdx.x;
  const int t0 = pt * 2;
  const int ip = t0 >> 8, jj = t0 & 255;
  const unsigned int* src = part + (size_t)tile0 * 32768 + (size_t)ip * 256 + jj;
  float s00 = 0.f, s01 = 0.f, s10 = 0.f, s11 = 0.f;
  for (int p = 0; p < np; ++p) {
    const uint2 v = *(const uint2*)&src[(size_t)p * 32768];
    s00 += b2f_lo(v.x); s10 += b2f_hi(v.x);
    s01 += b2f_lo(v.y); s11 += b2f_hi(v.y);
  }
  *(float2*)&dst[(size_t)(2 * ip) * 256 + jj] = make_float2(s00, s01);
  *(float2*)&dst[(size_t)(2 * ip + 1) * 256 + jj] = make_float2(s10, s11);
}

// ---------------- 2) Pv = G_b @ Wv^T  (256x512, K=256), 4 jobs ----------------
__global__ __launch_bounds__(256) void p_k(const float* __restrict__ Wv,
                                           float* __restrict__ ws) {
  const int job = blockIdx.z;
  const float* G = ws + o_Gs + (size_t)job * 65536;
  const float* W = Wv;
  float* P = ws + o_Pv + (size_t)job * 131072;
  const int c0 = blockIdx.x * 64, i0 = blockIdx.y * 64;
  __shared__ float Gt[64][68];
  __shared__ float Wt[64][68];
  const int tid = threadIdx.x;
  const int ty = tid >> 4, tx = tid & 15;
  float acc[4][4] = {};
  for (int k0 = 0; k0 < 256; k0 += 64) {
    __syncthreads();
#pragma unroll
    for (int pg = 0; pg < 4; ++pg) {
      const int idx = tid + pg * 256;
      const int row = idx >> 4, jq = (idx & 15) * 4;
      const float4 g = *(const float4*)&G[(size_t)(i0 + row) * DIN + k0 + jq];
      Gt[jq + 0][row] = g.x; Gt[jq + 1][row] = g.y; Gt[jq + 2][row] = g.z; Gt[jq + 3][row] = g.w;
      const float4 w = *(const float4*)&W[(size_t)(c0 + row) * DIN + k0 + jq];
      Wt[jq + 0][row] = w.x; Wt[jq + 1][row] = w.y; Wt[jq + 2][row] = w.z; Wt[jq + 3][row] = w.w;
    }
    __syncthreads();
#pragma unroll
    for (int k = 0; k < 64; ++k) {
      const float4 a = *(const float4*)&Gt[k][ty * 4];
      const float4 bb = *(const float4*)&Wt[k][tx * 4];
      const float av[4] = {a.x, a.y, a.z, a.w};
      const float bv_[4] = {bb.x, bb.y, bb.z, bb.w};
#pragma unroll
      for (int ii = 0; ii < 4; ++ii)
#pragma unroll
        for (int jj = 0; jj < 4; ++jj) acc[ii][jj] += av[ii] * bv_[jj];
    }
  }
#pragma unroll
  for (int ii = 0; ii < 4; ++ii)
    *(float4*)&P[(size_t)(i0 + ty * 4 + ii) * DOUT + c0 + tx * 4] =
        make_float4(acc[ii][0], acc[ii][1], acc[ii][2], acc[ii][3]);
}

// ---------------- 3) s2: wku/wvu/sums + norms via <G, S>_F ----------------
// grid (8, 5): job<4 -> batch b; job 4 -> query norm.
__global__ __launch_bounds__(256) void s2_k(const float* __restrict__ Wq,
                                            const float* __restrict__ Wk,
                                            const float* __restrict__ Wv,
                                            const float* __restrict__ bq,
                                            const float* __restrict__ bk,
                                            const float* __restrict__ bv,
                                            float* __restrict__ ws) {
  const int tid = threadIdx.x;
  const int bx = blockIdx.x;
  const int c = bx * 64 + (tid >> 2);
  const int part = tid & 3;
  const int i0 = part * 64;
  const int job = blockIdx.y;
  __shared__ float red[256];
  float total = 0.f;
  if (job < 4) {
    const int b = job;
    const float* ub = ws + o_us + b * 256;
    const float* wkr = Wk + (size_t)c * 256;
    const float* wvr = Wv + (size_t)c * 256;
    float dku = 0.f, dvu = 0.f;
#pragma unroll 4
    for (int t = 0; t < 16; ++t) {
      const float4 u4 = *(const float4*)&ub[i0 + t * 4];
      dku += dot4(*(const float4*)&wkr[i0 + t * 4], u4);
      dvu += dot4(*(const float4*)&wvr[i0 + t * 4], u4);
    }
    dku += __shfl_down(dku, 2); dku += __shfl_down(dku, 1);
    dvu += __shfl_down(dvu, 2); dvu += __shfl_down(dvu, 1);
    if (part == 0) {
      ws[o_wku + b * 512 + c] = dku;
      ws[o_wvu + b * 512 + c] = dvu;
      ws[o_kssum + b * 512 + c] = dku + (float)N_ * bk[c];
      ws[o_vssum + b * 512 + c] = dvu + (float)N_ * bv[c];
      total = 2.f * bk[c] * dku + (float)N_ * bk[c] * bk[c];
    }
    // Frobenius partial <G_b, S_K> over rows [bx*32, +32)
    const float* gp = ws + o_Gs + (size_t)b * 65536 + (size_t)bx * 8192;
    const float* sp = ws + o_SK + (size_t)bx * 8192;
#pragma unroll
    for (int it = 0; it < 8; ++it) {
      const int idx = it * 1024 + tid * 4;
      total += dot4v(*(const f32x4*)&gp[idx], *(const f32x4*)&sp[idx]);
    }
    red[tid] = total;
    __syncthreads();
    for (int s = 128; s > 0; s >>= 1) {
      if (tid < s) red[tid] += red[tid + s];
      __syncthreads();
    }
    if (tid == 0) atomicAdd(&ws[o_nrm + 1], red[0]);
  } else {
    const float* uq = ws + o_uq;
    const float* wqr = Wq + (size_t)c * 256;
    float dqu = 0.f;
#pragma unroll 4
    for (int t = 0; t < 16; ++t)
      dqu += dot4(*(const float4*)&wqr[i0 + t * 4], *(const float4*)&uq[i0 + t * 4]);
    dqu += __shfl_down(dqu, 2); dqu += __shfl_down(dqu, 1);
    if (part == 0) total = 2.f * bq[c] * dqu + (float)R_ * bq[c] * bq[c];
    const float* g1 = ws + o_Gq + (size_t)bx * 8192;
    const float* g2 = ws + o_Gq2 + (size_t)bx * 8192;
    const float* sp = ws + o_SQ + (size_t)bx * 8192;
#pragma unroll
    for (int it = 0; it < 8; ++it) {
      const int idx = it * 1024 + tid * 4;
      const f32x4 g = *(const f32x4*)&g1[idx] + *(const f32x4*)&g2[idx];
      total += dot4v(g, *(const f32x4*)&sp[idx]);
    }
    red[tid] = total;
    __syncthreads();
    for (int s = 128; s > 0; s >>= 1) {
      if (tid < s) red[tid] += red[tid + s];
      __syncthreads();
    }
    if (tid == 0) atomicAdd(&ws[o_nrm], red[0]);
  }
}

// ---------------- 4) kv[b,h] = Wk_h @ Pv[:, h-cols] + rank-1 (tiled, coalesced) ----------------
// grid (32): one block per (b,h). 256 threads.
__global__ __launch_bounds__(256) void kv_k(const float* __restrict__ Wk,
                                            const float* __restrict__ bk,
                                            const float* __restrict__ bv,
                                            float* __restrict__ ws) {
  const int bh = blockIdx.x, b = bh >> 3, h = bh & 7;
  const int tid = threadIdx.x;
  const int ty = tid >> 4, tx = tid & 15;
  __shared__ float As[32][68];   // [k][m]
  __shared__ float Bs[32][68];   // [k][d]
  float acc[4][4] = {};
  const int am = tid >> 2, ak = (tid & 3) * 8;       // A staging: row m, 8 k's
  const int bk_ = tid >> 3, bd = (tid & 7) * 8;      // B staging: row k, 8 d's
  for (int k0 = 0; k0 < 256; k0 += 32) {
    const float* wkp = Wk + (size_t)(h * 64 + am) * 256 + k0 + ak;
    const f32x4 a0 = *(const f32x4*)wkp;
    const f32x4 a1 = *(const f32x4*)(wkp + 4);
    const float* pvp = ws + o_Pv + (size_t)b * 131072 + (size_t)(k0 + bk_) * 512 + h * 64 + bd;
    const f32x4 b0 = *(const f32x4*)pvp;
    const f32x4 b1 = *(const f32x4*)(pvp + 4);
    __syncthreads();
#pragma unroll
    for (int e = 0; e < 4; ++e) As[ak + e][am] = a0[e];
#pragma unroll
    for (int e = 0; e < 4; ++e) As[ak + 4 + e][am] = a1[e];
    *(f32x4*)&Bs[bk_][bd] = b0;
    *(f32x4*)&Bs[bk_][bd + 4] = b1;
    __syncthreads();
#pragma unroll
    for (int k = 0; k < 32; ++k) {
      const f32x4 av = *(const f32x4*)&As[k][ty * 4];
      const f32x4 bv4 = *(const f32x4*)&Bs[k][tx * 4];
#pragma unroll
      for (int i = 0; i < 4; ++i)
#pragma unroll
        for (int j = 0; j < 4; ++j) acc[i][j] += av[i] * bv4[j];
    }
  }
  // rank-1 terms + store
  const f32x4 wvu4 = *(const f32x4*)&ws[o_wvu + b * 512 + h * 64 + tx * 4];
  const f32x4 bv4g = *(const f32x4*)&bv[h * 64 + tx * 4];
#pragma unroll
  for (int i = 0; i < 4; ++i) {
    const int m = ty * 4 + i;
    const float wkum = ws[o_wku + b * 512 + h * 64 + m];
    const float bkm = bk[h * 64 + m];
    f32x4 rr;
#pragma unroll
    for (int j = 0; j < 4; ++j)
      rr[j] = acc[i][j] + wkum * bv4g[j] + bkm * wvu4[j] + (float)N_ * bkm * bv4g[j];
    *(f32x4*)&ws[o_kv + (size_t)bh * 4096 + (size_t)m * 64 + tx * 4] = rr;
  }
}

// ---------------- 5) W1bt/w2bt/C1/C2 per (b,h): M = kv_h^T @ Wq_h ----------------
// grid (32): one block per (b,h). 256 threads.
__global__ __launch_bounds__(256) void w1_k(const float* __restrict__ Wq,
                                            const float* __restrict__ bq,
                                            float* __restrict__ ws) {
  const int bh = blockIdx.x, b = bh >> 3, h = bh & 7;
  const int tid = threadIdx.x;
  const int ty = tid >> 4, tx = tid & 15;   // out: d = ty*4+e, i = i0 + tx*8+j
  __shared__ float kvs[64][68];
  __shared__ float Ws[64][132];
  __shared__ float kssL[64];
  __shared__ float bqL[64];
  const float s = 1.f / (sqrtf(ws[o_nrm]) * sqrtf(ws[o_nrm + 1]));
  {
    const int m = tid >> 2, d0 = (tid & 3) * 16;
    const float* kvp = ws + o_kv + (size_t)bh * 4096 + (size_t)m * 64 + d0;
#pragma unroll
    for (int g = 0; g < 4; ++g) *(f32x4*)&kvs[m][d0 + g * 4] = *(const f32x4*)(kvp + g * 4);
    if (tid < 64) {
      kssL[tid] = ws[o_kssum + b * 512 + h * 64 + tid];
      bqL[tid] = bq[h * 64 + tid];
    }
  }
  unsigned short* W1bt = (unsigned short*)(ws + o_W1bt) + (size_t)b * 131072;
  unsigned short* w2bt = (unsigned short*)(ws + o_w2bt) + b * 4096;
#pragma unroll
  for (int it = 0; it < 2; ++it) {
    const int i0 = it * 128;
    __syncthreads();
    {
      const int m = tid >> 1, ioff = (tid & 1) * 64;
      const float* wqp = Wq + (size_t)(h * 64 + m) * 256 + i0 + ioff;
#pragma unroll
      for (int g = 0; g < 16; ++g) *(f32x4*)&Ws[m][ioff + g * 4] = *(const f32x4*)(wqp + g * 4);
    }
    __syncthreads();
    float acc[4][8] = {};
#pragma unroll 4
    for (int m = 0; m < 64; ++m) {
      const f32x4 a = *(const f32x4*)&kvs[m][ty * 4];
      const f32x4 w0 = *(const f32x4*)&Ws[m][tx * 8];
      const f32x4 w1 = *(const f32x4*)&Ws[m][tx * 8 + 4];
#pragma unroll
      for (int e = 0; e < 4; ++e) {
#pragma unroll
        for (int j = 0; j < 4; ++j) {
          acc[e][j] += a[e] * w0[j];
          acc[e][4 + j] += a[e] * w1[j];
        }
      }
    }
#pragma unroll
    for (int e = 0; e < 4; ++e) {
      short8 p;
#pragma unroll
      for (int j = 0; j < 8; ++j) p[j] = (short)f2b(s * acc[e][j]);
      *(short8*)&W1bt[(size_t)(h * 64 + ty * 4 + e) * 256 + i0 + tx * 8] = p;
    }
    if (tid < 128) {
      float w2v = 0.f;
#pragma unroll 8
      for (int m = 0; m < 64; ++m) w2v += kssL[m] * Ws[m][tid];
      w2bt[h * 256 + i0 + tid] = f2b(s * w2v);
      w2bt[(h + 8) * 256 + i0 + tid] = 0;
    }
  }
  if (tid < 64) {
    float c1 = 0.f;
#pragma unroll 8
    for (int m = 0; m < 64; ++m) c1 += bqL[m] * kvs[m][tid];
    ws[o_C1 + b * 512 + h * 64 + tid] = s * c1 + ws[o_vssum + b * 512 + h * 64 + tid];
  }
  if (tid == 0) {
    float c2 = 0.f;
    for (int m = 0; m < 64; ++m) c2 += bqL[m] * kssL[m];
    ws[o_C2 + b * 8 + h] = s * c2 + (float)N_;
  }
}

// ---------------- 6) output: num/den via bf16 MFMA + fused epilogue ----------------
__global__ __launch_bounds__(256) void out_k(const float* __restrict__ X,
                                             const float* __restrict__ ws,
                                             float* __restrict__ out) {
  const int r0 = blockIdx.x * 64;
  const int b = blockIdx.x >> 8;
  const int tid = threadIdx.x;
  const int lane = tid & 63, wv = tid >> 6;
  const int lc = lane & 15;
  const int klb = (lane >> 4) * 16;

  __shared__ __align__(16) unsigned short Xs[64 * 256];
  __shared__ float invden[64][9];
  char* Xb = (char*)Xs;

  {
    const int row = tid >> 2, kq = (tid & 3) * 64;
    const float* src = X + (size_t)(r0 + row) * DIN + kq;
    const int swz = (row & 7) << 4;
#pragma unroll
    for (int g = 0; g < 8; ++g) {
      const float4 v0 = *(const float4*)(src + g * 8);
      const float4 v1 = *(const float4*)(src + g * 8 + 4);
      short8 p;
      p[0] = (short)f2b(v0.x); p[1] = (short)f2b(v0.y);
      p[2] = (short)f2b(v0.z); p[3] = (short)f2b(v0.w);
      p[4] = (short)f2b(v1.x); p[5] = (short)f2b(v1.y);
      p[6] = (short)f2b(v1.z); p[7] = (short)f2b(v1.w);
      *(short8*)(Xb + ((row * 512 + (kq + g * 8) * 2) ^ swz)) = p;
    }
  }
  __syncthreads();

  const char* W1b = (const char*)((const unsigned short*)(ws + o_W1bt) + (size_t)b * 131072);
  const char* w2b = (const char*)((const unsigned short*)(ws + o_w2bt) + b * 4096);

  f32x4 acc[4][8] = {};
  f32x4 acc2[4] = {};
#pragma unroll
  for (int k32 = 0; k32 < 8; ++k32) {
    const int kbyte = k32 * 64;
    short8 a[4];
#pragma unroll
    for (int fi = 0; fi < 4; ++fi) {
      const int row = fi * 16 + lc;
      a[fi] = *(const short8*)(Xb + ((row * 512 + kbyte + klb) ^ ((row & 7) << 4)));
    }
    short8 bb[8];
#pragma unroll
    for (int fj = 0; fj < 8; ++fj) {
      const int cc = fj * 64 + wv * 16 + lc;
      bb[fj] = *(const short8*)(W1b + cc * 512 + kbyte + klb);
    }
    if (wv == 0) {
      const short8 b2 = *(const short8*)(w2b + lc * 512 + kbyte + klb);
#pragma unroll
      for (int fi = 0; fi < 4; ++fi)
        acc2[fi] = __builtin_amdgcn_mfma_f32_16x16x32_bf16(a[fi], b2, acc2[fi], 0, 0, 0);
    }
#pragma unroll
    for (int fi = 0; fi < 4; ++fi)
#pragma unroll
      for (int fj = 0; fj < 8; ++fj)
        acc[fi][fj] = __builtin_amdgcn_mfma_f32_16x16x32_bf16(a[fi], bb[fj], acc[fi][fj], 0, 0, 0);
  }

  if (wv == 0 && lc < 8) {
    const float c2 = ws[o_C2 + b * 8 + lc];
#pragma unroll
    for (int fi = 0; fi < 4; ++fi) {
      const int rb = fi * 16 + (lane >> 4) * 4;
#pragma unroll
      for (int r = 0; r < 4; ++r) invden[rb + r][lc] = 1.f / (acc2[fi][r] + c2);
    }
  }
  __syncthreads();

  const float* C1p = ws + o_C1 + b * 512;
  float cf[8];
#pragma unroll
  for (int fj = 0; fj < 8; ++fj) cf[fj] = C1p[fj * 64 + wv * 16 + lc];

#pragma unroll
  for (int fi = 0; fi < 4; ++fi) {
    const int rb = fi * 16 + (lane >> 4) * 4;
    float o[4] = {0.f, 0.f, 0.f, 0.f};
#pragma unroll
    for (int fj = 0; fj < 8; ++fj)
#pragma unroll
      for (int r = 0; r < 4; ++r)
        o[r] += (acc[fi][fj][r] + cf[fj]) * invden[rb + r][fj];
#pragma unroll
    for (int r = 0; r < 4; ++r)
      out[(size_t)(r0 + rb + r) * 64 + wv * 16 + lc] = o[r] * 0.125f;
  }
}

extern "C" void kernel_launch(void* const* d_in, const int* in_sizes, int n_in,
                              void* d_out, int out_size, void* d_ws, size_t ws_size,
                              hipStream_t stream) {
  const float* Xq = (const float*)d_in[0];
  const float* Xsrc = (const float*)d_in[1];
  const float* Wq = (const float*)d_in[2];
  const float* bq = (const float*)d_in[3];
  const float* Wk = (const float*)d_in[4];
  const float* bk = (const float*)d_in[5];
  const float* Wv = (const float*)d_in[6];
  const float* bv = (const float*)d_in[7];
  float* out = (float*)d_out;
  float* ws = (float*)d_ws;
  if (ws_size < WS_FLOATS * sizeof(float)) return;  // need >= 5.9 MB scratch

  int nb = 0;
  if (ws_size >= TIER1_FLOATS * sizeof(float)) nb = 64;
  else if (ws_size >= TIER2_FLOATS * sizeof(float)) nb = 32;
  unsigned int* part = nb ? (unsigned int*)(ws + o_part) : nullptr;

  if (nb) {
    // zero S_K/S_Q + colsums + norms (atomic-accumulated)
    hipMemsetAsync(ws + o_SK, 0, (ZERO_END - o_SK) * sizeof(float), stream);
    wgram_k<<<dim3(8, 2), 512, 0, stream>>>(Wk, Wq, ws);
    gram_k<<<dim3(nb, 8), 512, 0, stream>>>(Xq, Xsrc, ws, part);
    gred_k<<<dim3(64, 6), 256, 0, stream>>>(part, ws, nb);
  } else {
    hipMemsetAsync(ws, 0, ZERO_END * sizeof(float), stream);
    wgram_k<<<dim3(8, 2), 512, 0, stream>>>(Wk, Wq, ws);
    gram_k<<<dim3(32, 8), 512, 0, stream>>>(Xq, Xsrc, ws, nullptr);
  }
  p_k<<<dim3(8, 4, 4), 256, 0, stream>>>(Wv, ws);
  s2_k<<<dim3(8, 5), 256, 0, stream>>>(Wq, Wk, Wv, bq, bk, bv, ws);
  kv_k<<<32, 256, 0, stream>>>(Wk, bk, bv, ws);
  w1_k<<<32, 256, 0, stream>>>(Wq, bq, ws);
  out_k<<<dim3(1024), 256, 0, stream>>>(Xq, ws, out);
}

// Round 9
// 182.473 us; speedup vs baseline: 1.1374x; 1.1246x over previous
//
#include <hip/hip_runtime.h>
#include <math.h>

constexpr int B_ = 4;
constexpr int N_ = 16384;
constexpr int DIN = 256;
constexpr int DOUT = 512;
constexpr int R_ = B_ * N_;   // 65536

typedef __attribute__((ext_vector_type(4))) float f32x4;
typedef __attribute__((ext_vector_type(8))) short short8;

// ---------------- workspace layout (float offsets) ----------------
constexpr size_t o_Gq    = 0;         // 256x256 query gram, part 0
constexpr size_t o_Gq2   = 65536;     // 256x256 query gram, part 1
constexpr size_t o_Gs    = 131072;    // 4 x 256x256 per-batch source grams
constexpr size_t o_SK    = 393216;    // 256x256 Wk^T Wk   (atomic-accumulated)
constexpr size_t o_SQ    = 458752;    // 256x256 Wq^T Wq   (atomic-accumulated)
constexpr size_t o_uq    = 524288;    // 256 colsum(query)
constexpr size_t o_us    = 524544;    // 4x256 colsum(source_b)
constexpr size_t o_nrm   = 525568;    // [0]=nq2 [1]=nk2
constexpr size_t ZERO_END = 525570;   // atomic region: o_SK..here (fast), 0..here (fallback)
constexpr size_t o_Pv    = 525632;    // 4 x (256x512): G_b @ Wv^T
constexpr size_t o_wku   = 1049920;   // 4x512
constexpr size_t o_wvu   = 1051968;   // 4x512
constexpr size_t o_kssum = 1054016;   // 4x512
constexpr size_t o_vssum = 1056064;   // 4x512
constexpr size_t o_kv    = 1058112;   // 4x8x64x64 raw K^T V
constexpr size_t o_W1bt  = 1189184;   // bf16: 4 x [512 c][256 k]  (s folded in)
constexpr size_t o_w2bt  = 1451328;   // bf16: 4 x [16 c][256 k]   (rows 8..15 zero)
constexpr size_t o_C1    = 1459520;   // 4x512 fp32
constexpr size_t o_C2    = 1461568;   // 4x8 fp32
constexpr size_t WS_FLOATS = 1461600; // ~5.9 MB (minimum)
// gram partials: 512 half-tiles x 16384 u32 ([64 row-pairs][256 cols], bf16x2)
constexpr size_t o_part  = WS_FLOATS;
constexpr size_t PART_U32 = (size_t)512 * 16384;          // 33.5 MB
constexpr size_t TIER_FLOATS = WS_FLOATS + PART_U32;      // ~39.4 MB total

static __device__ __forceinline__ float dot4(float4 a, float4 b) {
  return a.x * b.x + a.y * b.y + a.z * b.z + a.w * b.w;
}
static __device__ __forceinline__ float dot4v(f32x4 a, f32x4 b) {
  return a[0] * b[0] + a[1] * b[1] + a[2] * b[2] + a[3] * b[3];
}

// fp32 -> bf16 bits, round-to-nearest-even
static __device__ __forceinline__ unsigned short f2b(float f) {
  unsigned int u = __float_as_uint(f);
  u = (u + 0x7FFFu + ((u >> 16) & 1u)) >> 16;
  return (unsigned short)u;
}
static __device__ __forceinline__ float b2f_lo(unsigned int u) {
  return __uint_as_float(u << 16);
}
static __device__ __forceinline__ float b2f_hi(unsigned int u) {
  return __uint_as_float(u & 0xFFFF0000u);
}

#define SWZ2(c) ((((c) >> 1) & 7) << 4)

// ---------------- 1) Grams: G = A^T A (256x256) + colsum, bf16 MFMA ----------------
// 512 blocks, 512 thr, wave tile 64x64 (acc=64 AGPR) -> <=128 regs/wave via
// __launch_bounds__(512,4) -> 2 blocks/CU co-resident (the R2..R8 versions were
// register-locked to 1 block/CU = 24.6 GB/s/CU share = the measured 62us).
// Block (z, rowblk, ihalf): G[ihalf*128..+128, :] from rows [rowblk*512, +512).
// ihalf-siblings mapped to the SAME XCD (in-kernel swizzle) so the duplicate
// row reads hit L2. Single 32KB LDS buffer; loads issued before barrier.
__global__ __launch_bounds__(512, 4) void gram_k(const float* __restrict__ Xq,
                                                 const float* __restrict__ Xsrc,
                                                 float* __restrict__ ws,
                                                 unsigned int* __restrict__ part) {
  const int g = blockIdx.x;                 // [0,512)
  const int cpx = g >> 3;                   // per-XCD sequence [0,64)
  const int ihalf = cpx & 1;
  const int pairIdx = (g & 7) * 32 + (cpx >> 1);   // [0,256)
  const int z = pairIdx >> 5;
  const int rowblk = pairIdx & 31;
  const float* A;
  float* G;
  float* u;
  if (z < 4) {
    A = Xsrc + (size_t)z * N_ * DIN;
    G = ws + o_Gs + (size_t)z * 65536;
    u = ws + o_us + z * 256;
  } else {
    A = Xq + (size_t)(z - 4) * N_ * DIN;
    G = ws + ((z & 2) ? o_Gq2 : o_Gq);
    u = ws + o_uq;
  }
  const int row0 = rowblk * 512;
  const int tid = threadIdx.x;
  const int lane = tid & 63, wv = tid >> 6;
  const int i0w = ihalf * 128 + (wv >> 2) * 64;   // absolute i-col base
  const int j0w = (wv & 3) * 64;
  const int lc = lane & 15;
  const int klb = (lane >> 4) * 16;

  __shared__ __align__(16) unsigned short As[256 * 64];   // 32 KB single buffer
  char* Ab = (char*)As;

  const int cg = tid & 63;
  const int wq = tid >> 6;
  float cs[4] = {0.f, 0.f, 0.f, 0.f};
  f32x4 acc[4][4] = {};

  for (int q = 0; q < 8; ++q) {
    // issue loads BEFORE the barrier: in flight while prior compute finishes
    const float* src = A + (size_t)(row0 + q * 64 + wq * 8) * DIN + cg * 4;
    f32x4 v[8];
#pragma unroll
    for (int gg = 0; gg < 8; ++gg) v[gg] = *(const f32x4*)(src + (size_t)gg * DIN);
    __syncthreads();   // prior compute done reading LDS
#pragma unroll
    for (int gg = 0; gg < 8; ++gg)
#pragma unroll
      for (int j = 0; j < 4; ++j) cs[j] += v[gg][j];
#pragma unroll
    for (int j = 0; j < 4; ++j) {
      short8 p;
#pragma unroll
      for (int e = 0; e < 8; ++e) p[e] = (short)f2b(v[e][j]);
      const int c = cg * 4 + j;
      *(short8*)(Ab + ((c * 128 + wq * 16) ^ SWZ2(c))) = p;
    }
    __syncthreads();
#pragma unroll
    for (int ks = 0; ks < 2; ++ks) {
      const int kbyte = ks * 64 + klb;
      short8 a[4];
#pragma unroll
      for (int fi = 0; fi < 4; ++fi) {
        const int cc = i0w + fi * 16 + lc;
        a[fi] = *(const short8*)(Ab + ((cc * 128 + kbyte) ^ SWZ2(cc)));
      }
#pragma unroll
      for (int fj = 0; fj < 4; ++fj) {
        const int cc = j0w + fj * 16 + lc;
        const short8 b = *(const short8*)(Ab + ((cc * 128 + kbyte) ^ SWZ2(cc)));
#pragma unroll
        for (int fi = 0; fi < 4; ++fi)
          acc[fi][fj] = __builtin_amdgcn_mfma_f32_16x16x32_bf16(a[fi], b, acc[fi][fj], 0, 0, 0);
      }
    }
  }

  if (part) {
    // bf16-packed half-tile: u32 [64 row-pairs][256 cols]
    unsigned int* P = part + ((size_t)(z * 32 + rowblk) * 2 + ihalf) * 16384;
#pragma unroll
    for (int fi = 0; fi < 4; ++fi) {
      const int lr = (wv >> 2) * 64 + fi * 16 + (lane >> 4) * 4;  // local row [0,128)
#pragma unroll
      for (int fj = 0; fj < 4; ++fj) {
        const int jb = j0w + fj * 16 + lc;
        const unsigned int p0 = (unsigned int)f2b(acc[fi][fj][0]) |
                                ((unsigned int)f2b(acc[fi][fj][1]) << 16);
        const unsigned int p1 = (unsigned int)f2b(acc[fi][fj][2]) |
                                ((unsigned int)f2b(acc[fi][fj][3]) << 16);
        P[(size_t)(lr >> 1) * 256 + jb] = p0;
        P[(size_t)((lr >> 1) + 1) * 256 + jb] = p1;
      }
    }
  } else {
    // fallback: fp32 device atomics into G
#pragma unroll
    for (int fi = 0; fi < 4; ++fi) {
      const int ib = i0w + fi * 16 + (lane >> 4) * 4;
#pragma unroll
      for (int fj = 0; fj < 4; ++fj) {
        const int jb = j0w + fj * 16 + lc;
#pragma unroll
        for (int r = 0; r < 4; ++r)
          atomicAdd(&G[(size_t)(ib + r) * DIN + jb], acc[fi][fj][r]);
      }
    }
  }

  // colsum: both halves staged the same rows -> only ihalf 0 contributes
  __syncthreads();
  float* red = (float*)As;
  *(float4*)&red[wq * 256 + cg * 4] = make_float4(cs[0], cs[1], cs[2], cs[3]);
  __syncthreads();
  if (ihalf == 0 && tid < 256) {
    float s = 0.f;
#pragma unroll
    for (int pp = 0; pp < 8; ++pp) s += red[pp * 256 + tid];
    atomicAdd(&u[tid], s);
  }
}

// ---------------- 1w) weight grams: S_K = Wk^T Wk, S_Q = Wq^T Wq ----------------
__global__ __launch_bounds__(512) void wgram_k(const float* __restrict__ Wk,
                                               const float* __restrict__ Wq,
                                               float* __restrict__ ws) {
  const int z = blockIdx.y;
  const float* A = z ? Wq : Wk;
  float* S = ws + (z ? o_SQ : o_SK);
  const int row0 = blockIdx.x * 64;
  const int tid = threadIdx.x;
  const int lane = tid & 63, wv = tid >> 6;
  const int i0w = (wv >> 1) * 64;
  const int j0w = (wv & 1) * 128;
  const int lc = lane & 15;
  const int klb = (lane >> 4) * 16;

  __shared__ __align__(16) unsigned short As[256 * 64];
  char* Ab = (char*)As;

  const int cg = tid & 63;
  const int wq = tid >> 6;
  {
    const float* src = A + (size_t)(row0 + wq * 8) * DIN + cg * 4;
    f32x4 v[8];
#pragma unroll
    for (int g = 0; g < 8; ++g) v[g] = *(const f32x4*)(src + (size_t)g * DIN);
#pragma unroll
    for (int j = 0; j < 4; ++j) {
      short8 p;
#pragma unroll
      for (int e = 0; e < 8; ++e) p[e] = (short)f2b(v[e][j]);
      const int c = cg * 4 + j;
      *(short8*)(Ab + ((c * 128 + wq * 16) ^ SWZ2(c))) = p;
    }
  }
  __syncthreads();
  f32x4 acc[4][8] = {};
#pragma unroll
  for (int ks = 0; ks < 2; ++ks) {
    const int kbyte = ks * 64;
    short8 a[4], b[8];
#pragma unroll
    for (int fi = 0; fi < 4; ++fi) {
      const int cc = i0w + fi * 16 + lc;
      a[fi] = *(const short8*)(Ab + ((cc * 128 + kbyte + klb) ^ SWZ2(cc)));
    }
#pragma unroll
    for (int fj = 0; fj < 8; ++fj) {
      const int cc = j0w + fj * 16 + lc;
      b[fj] = *(const short8*)(Ab + ((cc * 128 + kbyte + klb) ^ SWZ2(cc)));
    }
#pragma unroll
    for (int fi = 0; fi < 4; ++fi)
#pragma unroll
      for (int fj = 0; fj < 8; ++fj)
        acc[fi][fj] = __builtin_amdgcn_mfma_f32_16x16x32_bf16(a[fi], b[fj], acc[fi][fj], 0, 0, 0);
  }
#pragma unroll
  for (int fi = 0; fi < 4; ++fi) {
    const int ib = i0w + fi * 16 + (lane >> 4) * 4;
#pragma unroll
    for (int fj = 0; fj < 8; ++fj) {
      const int jb = j0w + fj * 16 + lc;
#pragma unroll
      for (int r = 0; r < 4; ++r)
        atomicAdd(&S[(size_t)(ib + r) * DIN + jb], acc[fi][fj][r]);
    }
  }
}

// ---------------- 1b) reduce bf16 gram half-tile partials -> fp32 G ----------------
// part tile T=(z*32+rowblk) in [0,256), each T has 2 halves of 16384 u32.
// grid (64, 6): j<4 -> Gs[j] (T0=j*32, np=32); j=4 -> Gq (T0=128, np=64);
// j=5 -> Gq2 (T0=192, np=64).
__global__ __launch_bounds__(256) void gred_k(const unsigned int* __restrict__ part,
                                              float* __restrict__ ws) {
  const int j = blockIdx.y;
  int T0, np;
  float* dst;
  if (j < 4) {
    T0 = j * 32; np = 32; dst = ws + o_Gs + (size_t)j * 65536;
  } else if (j == 4) {
    T0 = 128; np = 64; dst = ws + o_Gq;
  } else {
    T0 = 192; np = 64; dst = ws + o_Gq2;
  }
  const int pt = blockIdx.x * 256 + threadIdx.x;   // [0,16384)
  const int t0 = pt * 2;
  const int ip = t0 >> 8, jj = t0 & 255;           // ip = row-pair [0,128)
  const int ihalf = ip >> 6, ipl = ip & 63;
  const unsigned int* src =
      part + ((size_t)(T0)*2 + ihalf) * 16384 + (size_t)ipl * 256 + jj;
  float s00 = 0.f, s01 = 0.f, s10 = 0.f, s11 = 0.f;
  for (int p = 0; p < np; ++p) {
    const uint2 v = *(const uint2*)&src[(size_t)p * 32768];
    s00 += b2f_lo(v.x); s10 += b2f_hi(v.x);
    s01 += b2f_lo(v.y); s11 += b2f_hi(v.y);
  }
  *(float2*)&dst[(size_t)(2 * ip) * 256 + jj] = make_float2(s00, s01);
  *(float2*)&dst[(size_t)(2 * ip + 1) * 256 + jj] = make_float2(s10, s11);
}

// ---------------- 2) Pv = G_b @ Wv^T  (256x512, K=256), 4 jobs ----------------
__global__ __launch_bounds__(256) void p_k(const float* __restrict__ Wv,
                                           float* __restrict__ ws) {
  const int job = blockIdx.z;
  const float* G = ws + o_Gs + (size_t)job * 65536;
  const float* W = Wv;
  float* P = ws + o_Pv + (size_t)job * 131072;
  const int c0 = blockIdx.x * 64, i0 = blockIdx.y * 64;
  __shared__ float Gt[64][68];
  __shared__ float Wt[64][68];
  const int tid = threadIdx.x;
  const int ty = tid >> 4, tx = tid & 15;
  float acc[4][4] = {};
  for (int k0 = 0; k0 < 256; k0 += 64) {
    __syncthreads();
#pragma unroll
    for (int pg = 0; pg < 4; ++pg) {
      const int idx = tid + pg * 256;
      const int row = idx >> 4, jq = (idx & 15) * 4;
      const float4 g = *(const float4*)&G[(size_t)(i0 + row) * DIN + k0 + jq];
      Gt[jq + 0][row] = g.x; Gt[jq + 1][row] = g.y; Gt[jq + 2][row] = g.z; Gt[jq + 3][row] = g.w;
      const float4 w = *(const float4*)&W[(size_t)(c0 + row) * DIN + k0 + jq];
      Wt[jq + 0][row] = w.x; Wt[jq + 1][row] = w.y; Wt[jq + 2][row] = w.z; Wt[jq + 3][row] = w.w;
    }
    __syncthreads();
#pragma unroll
    for (int k = 0; k < 64; ++k) {
      const float4 a = *(const float4*)&Gt[k][ty * 4];
      const float4 bb = *(const float4*)&Wt[k][tx * 4];
      const float av[4] = {a.x, a.y, a.z, a.w};
      const float bv_[4] = {bb.x, bb.y, bb.z, bb.w};
#pragma unroll
      for (int ii = 0; ii < 4; ++ii)
#pragma unroll
        for (int jj = 0; jj < 4; ++jj) acc[ii][jj] += av[ii] * bv_[jj];
    }
  }
#pragma unroll
  for (int ii = 0; ii < 4; ++ii)
    *(float4*)&P[(size_t)(i0 + ty * 4 + ii) * DOUT + c0 + tx * 4] =
        make_float4(acc[ii][0], acc[ii][1], acc[ii][2], acc[ii][3]);
}

// ---------------- 3) s2: wku/wvu/sums + norms via <G, S>_F ----------------
__global__ __launch_bounds__(256) void s2_k(const float* __restrict__ Wq,
                                            const float* __restrict__ Wk,
                                            const float* __restrict__ Wv,
                                            const float* __restrict__ bq,
                                            const float* __restrict__ bk,
                                            const float* __restrict__ bv,
                                            float* __restrict__ ws) {
  const int tid = threadIdx.x;
  const int bx = blockIdx.x;
  const int c = bx * 64 + (tid >> 2);
  const int part = tid & 3;
  const int i0 = part * 64;
  const int job = blockIdx.y;
  __shared__ float red[256];
  float total = 0.f;
  if (job < 4) {
    const int b = job;
    const float* ub = ws + o_us + b * 256;
    const float* wkr = Wk + (size_t)c * 256;
    const float* wvr = Wv + (size_t)c * 256;
    float dku = 0.f, dvu = 0.f;
#pragma unroll 4
    for (int t = 0; t < 16; ++t) {
      const float4 u4 = *(const float4*)&ub[i0 + t * 4];
      dku += dot4(*(const float4*)&wkr[i0 + t * 4], u4);
      dvu += dot4(*(const float4*)&wvr[i0 + t * 4], u4);
    }
    dku += __shfl_down(dku, 2); dku += __shfl_down(dku, 1);
    dvu += __shfl_down(dvu, 2); dvu += __shfl_down(dvu, 1);
    if (part == 0) {
      ws[o_wku + b * 512 + c] = dku;
      ws[o_wvu + b * 512 + c] = dvu;
      ws[o_kssum + b * 512 + c] = dku + (float)N_ * bk[c];
      ws[o_vssum + b * 512 + c] = dvu + (float)N_ * bv[c];
      total = 2.f * bk[c] * dku + (float)N_ * bk[c] * bk[c];
    }
    const float* gp = ws + o_Gs + (size_t)b * 65536 + (size_t)bx * 8192;
    const float* sp = ws + o_SK + (size_t)bx * 8192;
#pragma unroll
    for (int it = 0; it < 8; ++it) {
      const int idx = it * 1024 + tid * 4;
      total += dot4v(*(const f32x4*)&gp[idx], *(const f32x4*)&sp[idx]);
    }
    red[tid] = total;
    __syncthreads();
    for (int s = 128; s > 0; s >>= 1) {
      if (tid < s) red[tid] += red[tid + s];
      __syncthreads();
    }
    if (tid == 0) atomicAdd(&ws[o_nrm + 1], red[0]);
  } else {
    const float* uq = ws + o_uq;
    const float* wqr = Wq + (size_t)c * 256;
    float dqu = 0.f;
#pragma unroll 4
    for (int t = 0; t < 16; ++t)
      dqu += dot4(*(const float4*)&wqr[i0 + t * 4], *(const float4*)&uq[i0 + t * 4]);
    dqu += __shfl_down(dqu, 2); dqu += __shfl_down(dqu, 1);
    if (part == 0) total = 2.f * bq[c] * dqu + (float)R_ * bq[c] * bq[c];
    const float* g1 = ws + o_Gq + (size_t)bx * 8192;
    const float* g2 = ws + o_Gq2 + (size_t)bx * 8192;
    const float* sp = ws + o_SQ + (size_t)bx * 8192;
#pragma unroll
    for (int it = 0; it < 8; ++it) {
      const int idx = it * 1024 + tid * 4;
      const f32x4 g = *(const f32x4*)&g1[idx] + *(const f32x4*)&g2[idx];
      total += dot4v(g, *(const f32x4*)&sp[idx]);
    }
    red[tid] = total;
    __syncthreads();
    for (int s = 128; s > 0; s >>= 1) {
      if (tid < s) red[tid] += red[tid + s];
      __syncthreads();
    }
    if (tid == 0) atomicAdd(&ws[o_nrm], red[0]);
  }
}

// ---------------- 4) kv[b,h] = Wk_h @ Pv[:, h-cols] + rank-1 ----------------
__global__ __launch_bounds__(256) void kv_k(const float* __restrict__ Wk,
                                            const float* __restrict__ bk,
                                            const float* __restrict__ bv,
                                            float* __restrict__ ws) {
  const int bh = blockIdx.x, b = bh >> 3, h = bh & 7;
  const int tid = threadIdx.x;
  const int ty = tid >> 4, tx = tid & 15;
  __shared__ float As[32][68];
  __shared__ float Bs[32][68];
  float acc[4][4] = {};
  const int am = tid >> 2, ak = (tid & 3) * 8;
  const int bk_ = tid >> 3, bd = (tid & 7) * 8;
  for (int k0 = 0; k0 < 256; k0 += 32) {
    const float* wkp = Wk + (size_t)(h * 64 + am) * 256 + k0 + ak;
    const f32x4 a0 = *(const f32x4*)wkp;
    const f32x4 a1 = *(const f32x4*)(wkp + 4);
    const float* pvp = ws + o_Pv + (size_t)b * 131072 + (size_t)(k0 + bk_) * 512 + h * 64 + bd;
    const f32x4 b0 = *(const f32x4*)pvp;
    const f32x4 b1 = *(const f32x4*)(pvp + 4);
    __syncthreads();
#pragma unroll
    for (int e = 0; e < 4; ++e) As[ak + e][am] = a0[e];
#pragma unroll
    for (int e = 0; e < 4; ++e) As[ak + 4 + e][am] = a1[e];
    *(f32x4*)&Bs[bk_][bd] = b0;
    *(f32x4*)&Bs[bk_][bd + 4] = b1;
    __syncthreads();
#pragma unroll
    for (int k = 0; k < 32; ++k) {
      const f32x4 av = *(const f32x4*)&As[k][ty * 4];
      const f32x4 bv4 = *(const f32x4*)&Bs[k][tx * 4];
#pragma unroll
      for (int i = 0; i < 4; ++i)
#pragma unroll
        for (int j = 0; j < 4; ++j) acc[i][j] += av[i] * bv4[j];
    }
  }
  const f32x4 wvu4 = *(const f32x4*)&ws[o_wvu + b * 512 + h * 64 + tx * 4];
  const f32x4 bv4g = *(const f32x4*)&bv[h * 64 + tx * 4];
#pragma unroll
  for (int i = 0; i < 4; ++i) {
    const int m = ty * 4 + i;
    const float wkum = ws[o_wku + b * 512 + h * 64 + m];
    const float bkm = bk[h * 64 + m];
    f32x4 rr;
#pragma unroll
    for (int j = 0; j < 4; ++j)
      rr[j] = acc[i][j] + wkum * bv4g[j] + bkm * wvu4[j] + (float)N_ * bkm * bv4g[j];
    *(f32x4*)&ws[o_kv + (size_t)bh * 4096 + (size_t)m * 64 + tx * 4] = rr;
  }
}

// ---------------- 5) W1bt/w2bt/C1/C2 per (b,h): M = kv_h^T @ Wq_h ----------------
__global__ __launch_bounds__(256) void w1_k(const float* __restrict__ Wq,
                                            const float* __restrict__ bq,
                                            float* __restrict__ ws) {
  const int bh = blockIdx.x, b = bh >> 3, h = bh & 7;
  const int tid = threadIdx.x;
  const int ty = tid >> 4, tx = tid & 15;
  __shared__ float kvs[64][68];
  __shared__ float Ws[64][132];
  __shared__ float kssL[64];
  __shared__ float bqL[64];
  const float s = 1.f / (sqrtf(ws[o_nrm]) * sqrtf(ws[o_nrm + 1]));
  {
    const int m = tid >> 2, d0 = (tid & 3) * 16;
    const float* kvp = ws + o_kv + (size_t)bh * 4096 + (size_t)m * 64 + d0;
#pragma unroll
    for (int g = 0; g < 4; ++g) *(f32x4*)&kvs[m][d0 + g * 4] = *(const f32x4*)(kvp + g * 4);
    if (tid < 64) {
      kssL[tid] = ws[o_kssum + b * 512 + h * 64 + tid];
      bqL[tid] = bq[h * 64 + tid];
    }
  }
  unsigned short* W1bt = (unsigned short*)(ws + o_W1bt) + (size_t)b * 131072;
  unsigned short* w2bt = (unsigned short*)(ws + o_w2bt) + b * 4096;
#pragma unroll
  for (int it = 0; it < 2; ++it) {
    const int i0 = it * 128;
    __syncthreads();
    {
      const int m = tid >> 1, ioff = (tid & 1) * 64;
      const float* wqp = Wq + (size_t)(h * 64 + m) * 256 + i0 + ioff;
#pragma unroll
      for (int g = 0; g < 16; ++g) *(f32x4*)&Ws[m][ioff + g * 4] = *(const f32x4*)(wqp + g * 4);
    }
    __syncthreads();
    float acc[4][8] = {};
#pragma unroll 4
    for (int m = 0; m < 64; ++m) {
      const f32x4 a = *(const f32x4*)&kvs[m][ty * 4];
      const f32x4 w0 = *(const f32x4*)&Ws[m][tx * 8];
      const f32x4 w1 = *(const f32x4*)&Ws[m][tx * 8 + 4];
#pragma unroll
      for (int e = 0; e < 4; ++e) {
#pragma unroll
        for (int j = 0; j < 4; ++j) {
          acc[e][j] += a[e] * w0[j];
          acc[e][4 + j] += a[e] * w1[j];
        }
      }
    }
#pragma unroll
    for (int e = 0; e < 4; ++e) {
      short8 p;
#pragma unroll
      for (int j = 0; j < 8; ++j) p[j] = (short)f2b(s * acc[e][j]);
      *(short8*)&W1bt[(size_t)(h * 64 + ty * 4 + e) * 256 + i0 + tx * 8] = p;
    }
    if (tid < 128) {
      float w2v = 0.f;
#pragma unroll 8
      for (int m = 0; m < 64; ++m) w2v += kssL[m] * Ws[m][tid];
      w2bt[h * 256 + i0 + tid] = f2b(s * w2v);
      w2bt[(h + 8) * 256 + i0 + tid] = 0;
    }
  }
  if (tid < 64) {
    float c1 = 0.f;
#pragma unroll 8
    for (int m = 0; m < 64; ++m) c1 += bqL[m] * kvs[m][tid];
    ws[o_C1 + b * 512 + h * 64 + tid] = s * c1 + ws[o_vssum + b * 512 + h * 64 + tid];
  }
  if (tid == 0) {
    float c2 = 0.f;
    for (int m = 0; m < 64; ++m) c2 += bqL[m] * kssL[m];
    ws[o_C2 + b * 8 + h] = s * c2 + (float)N_;
  }
}

// ---------------- 6) output: num/den via bf16 MFMA + fused epilogue ----------------
__global__ __launch_bounds__(256) void out_k(const float* __restrict__ X,
                                             const float* __restrict__ ws,
                                             float* __restrict__ out) {
  const int r0 = blockIdx.x * 64;
  const int b = blockIdx.x >> 8;
  const int tid = threadIdx.x;
  const int lane = tid & 63, wv = tid >> 6;
  const int lc = lane & 15;
  const int klb = (lane >> 4) * 16;

  __shared__ __align__(16) unsigned short Xs[64 * 256];
  __shared__ float invden[64][9];
  char* Xb = (char*)Xs;

  {
    const int row = tid >> 2, kq = (tid & 3) * 64;
    const float* src = X + (size_t)(r0 + row) * DIN + kq;
    const int swz = (row & 7) << 4;
#pragma unroll
    for (int g = 0; g < 8; ++g) {
      const float4 v0 = *(const float4*)(src + g * 8);
      const float4 v1 = *(const float4*)(src + g * 8 + 4);
      short8 p;
      p[0] = (short)f2b(v0.x); p[1] = (short)f2b(v0.y);
      p[2] = (short)f2b(v0.z); p[3] = (short)f2b(v0.w);
      p[4] = (short)f2b(v1.x); p[5] = (short)f2b(v1.y);
      p[6] = (short)f2b(v1.z); p[7] = (short)f2b(v1.w);
      *(short8*)(Xb + ((row * 512 + (kq + g * 8) * 2) ^ swz)) = p;
    }
  }
  __syncthreads();

  const char* W1b = (const char*)((const unsigned short*)(ws + o_W1bt) + (size_t)b * 131072);
  const char* w2b = (const char*)((const unsigned short*)(ws + o_w2bt) + b * 4096);

  f32x4 acc[4][8] = {};
  f32x4 acc2[4] = {};
#pragma unroll
  for (int k32 = 0; k32 < 8; ++k32) {
    const int kbyte = k32 * 64;
    short8 a[4];
#pragma unroll
    for (int fi = 0; fi < 4; ++fi) {
      const int row = fi * 16 + lc;
      a[fi] = *(const short8*)(Xb + ((row * 512 + kbyte + klb) ^ ((row & 7) << 4)));
    }
    short8 bb[8];
#pragma unroll
    for (int fj = 0; fj < 8; ++fj) {
      const int cc = fj * 64 + wv * 16 + lc;
      bb[fj] = *(const short8*)(W1b + cc * 512 + kbyte + klb);
    }
    if (wv == 0) {
      const short8 b2 = *(const short8*)(w2b + lc * 512 + kbyte + klb);
#pragma unroll
      for (int fi = 0; fi < 4; ++fi)
        acc2[fi] = __builtin_amdgcn_mfma_f32_16x16x32_bf16(a[fi], b2, acc2[fi], 0, 0, 0);
    }
#pragma unroll
    for (int fi = 0; fi < 4; ++fi)
#pragma unroll
      for (int fj = 0; fj < 8; ++fj)
        acc[fi][fj] = __builtin_amdgcn_mfma_f32_16x16x32_bf16(a[fi], bb[fj], acc[fi][fj], 0, 0, 0);
  }

  if (wv == 0 && lc < 8) {
    const float c2 = ws[o_C2 + b * 8 + lc];
#pragma unroll
    for (int fi = 0; fi < 4; ++fi) {
      const int rb = fi * 16 + (lane >> 4) * 4;
#pragma unroll
      for (int r = 0; r < 4; ++r) invden[rb + r][lc] = 1.f / (acc2[fi][r] + c2);
    }
  }
  __syncthreads();

  const float* C1p = ws + o_C1 + b * 512;
  float cf[8];
#pragma unroll
  for (int fj = 0; fj < 8; ++fj) cf[fj] = C1p[fj * 64 + wv * 16 + lc];

#pragma unroll
  for (int fi = 0; fi < 4; ++fi) {
    const int rb = fi * 16 + (lane >> 4) * 4;
    float o[4] = {0.f, 0.f, 0.f, 0.f};
#pragma unroll
    for (int fj = 0; fj < 8; ++fj)
#pragma unroll
      for (int r = 0; r < 4; ++r)
        o[r] += (acc[fi][fj][r] + cf[fj]) * invden[rb + r][fj];
#pragma unroll
    for (int r = 0; r < 4; ++r)
      out[(size_t)(r0 + rb + r) * 64 + wv * 16 + lc] = o[r] * 0.125f;
  }
}

extern "C" void kernel_launch(void* const* d_in, const int* in_sizes, int n_in,
                              void* d_out, int out_size, void* d_ws, size_t ws_size,
                              hipStream_t stream) {
  const float* Xq = (const float*)d_in[0];
  const float* Xsrc = (const float*)d_in[1];
  const float* Wq = (const float*)d_in[2];
  const float* bq = (const float*)d_in[3];
  const float* Wk = (const float*)d_in[4];
  const float* bk = (const float*)d_in[5];
  const float* Wv = (const float*)d_in[6];
  const float* bv = (const float*)d_in[7];
  float* out = (float*)d_out;
  float* ws = (float*)d_ws;
  if (ws_size < WS_FLOATS * sizeof(float)) return;  // need >= 5.9 MB scratch

  const bool fast = ws_size >= TIER_FLOATS * sizeof(float);  // ~39.4 MB
  unsigned int* part = fast ? (unsigned int*)(ws + o_part) : nullptr;

  if (fast) {
    hipMemsetAsync(ws + o_SK, 0, (ZERO_END - o_SK) * sizeof(float), stream);
    wgram_k<<<dim3(8, 2), 512, 0, stream>>>(Wk, Wq, ws);
    gram_k<<<512, 512, 0, stream>>>(Xq, Xsrc, ws, part);
    gred_k<<<dim3(64, 6), 256, 0, stream>>>(part, ws);
  } else {
    hipMemsetAsync(ws, 0, ZERO_END * sizeof(float), stream);
    wgram_k<<<dim3(8, 2), 512, 0, stream>>>(Wk, Wq, ws);
    gram_k<<<512, 512, 0, stream>>>(Xq, Xsrc, ws, nullptr);
  }
  p_k<<<dim3(8, 4, 4), 256, 0, stream>>>(Wv, ws);
  s2_k<<<dim3(8, 5), 256, 0, stream>>>(Wq, Wk, Wv, bq, bk, bv, ws);
  kv_k<<<32, 256, 0, stream>>>(Wk, bk, bv, ws);
  w1_k<<<32, 256, 0, stream>>>(Wq, bq, ws);
  out_k<<<dim3(1024), 256, 0, stream>>>(Xq, ws, out);
}